// Round 10
// baseline (130.450 us; speedup 1.0000x reference)
//
#include <hip/hip_runtime.h>
#include <cstdint>
#include <cstddef>

#define Tn 1024
#define Bn 64
#define Cn 8
#define Nn 64
#define LDP 65             /* padded row stride for trans_lds */
#define TBC 512            /* tags stride per t */
#define ES 32768           /* emissions stride per t (B*C*N) */
#define GS ((size_t)4 * ES)  /* group stride: 4 t-slices */
#define LN2F 0.69314718056f

typedef float f32x2 __attribute__((ext_vector_type(2)));
typedef float f32x4 __attribute__((ext_vector_type(4)));

// ---- wave64 reductions via DPP ----
__device__ __forceinline__ float wred_max(float x) {
  int v;
#define STEP(ctrl) \
  v = __builtin_amdgcn_update_dpp((int)0xff800000, __float_as_int(x), ctrl, 0xf, 0xf, false); \
  x = fmaxf(x, __int_as_float(v));
  STEP(0x111) STEP(0x112) STEP(0x114) STEP(0x118) STEP(0x142) STEP(0x143)
#undef STEP
  return __int_as_float(__builtin_amdgcn_readlane(__float_as_int(x), 63));
}

__device__ __forceinline__ float wred_sum(float x) {
  int v;
#define STEP(ctrl) \
  v = __builtin_amdgcn_update_dpp(0, __float_as_int(x), ctrl, 0xf, 0xf, false); \
  x = x + __int_as_float(v);
  STEP(0x111) STEP(0x112) STEP(0x114) STEP(0x118) STEP(0x142) STEP(0x143)
#undef STEP
  return __int_as_float(__builtin_amdgcn_readlane(__float_as_int(x), 63));
}

__device__ __forceinline__ float lane0(float x) {
  return __int_as_float(__builtin_amdgcn_readlane(__float_as_int(x), 0));
}

// ---- half-split LDS-broadcast 64x64 matvec ----
// Lane j writes u_j to ew[j]. Lanes <32 read quads 0..7 (sources 0..31),
// lanes >=32 read quads 8..15 (sources 32..63) — uniform per half-wave
// (max 2 distinct addresses/read -> 2-way broadcast, free), 8 ds_read_b128.
// Each lane accumulates its 32 sources for the OUTPUT PAIR (L, L^32) as
// packed f32x2. The missing half-sum is recovered via v_permlane32_swap_b32
// with a DIRECTION-AGNOSTIC combine: both asm operands start equal, so after
// the swap exactly one holds the partner value: partner = x_ + y_ - Ax_.y.
#define MQ2(t_, base) \
  A0_ += (t_).x * P2[(base) + 0]; \
  A1_ += (t_).y * P2[(base) + 1]; \
  A2_ += (t_).z * P2[(base) + 2]; \
  A3_ += (t_).w * P2[(base) + 3];

#define MVBODY() \
  f32x2 A0_ = {0.f, 0.f}, A1_ = A0_, A2_ = A0_, A3_ = A0_; \
  { const f32x4* q_ = ((const f32x4*)ew) + hb8; \
    f32x4 t_; \
    t_ = q_[0]; MQ2(t_, 0)   t_ = q_[1]; MQ2(t_, 4) \
    t_ = q_[2]; MQ2(t_, 8)   t_ = q_[3]; MQ2(t_, 12) \
    t_ = q_[4]; MQ2(t_, 16)  t_ = q_[5]; MQ2(t_, 20) \
    t_ = q_[6]; MQ2(t_, 24)  t_ = q_[7]; MQ2(t_, 28) } \
  f32x2 Ax_ = (A0_ + A1_) + (A2_ + A3_); \
  float own_ = Ax_.x; \
  float x_ = Ax_.y, y_ = Ax_.y; \
  asm("v_permlane32_swap_b32 %0, %1" : "+v"(x_), "+v"(y_)); \
  float s_ = own_ + ((x_ + y_) - Ax_.y);

// Linear-space forward step: u'_j = w_j * sum_i P_ij u_i
#define FSTEP_LIN(u, wv) do {                       \
    ew[lane] = (u);                                 \
    MVBODY();                                       \
    (u) = s_ * (wv);                                \
  } while (0)

// Linear-space backward step: v_i = sum_j P_ij (w_j v'_j)
#define BSTEP_LIN(v, wv) do {                       \
    ew[lane] = (v) * (wv);                          \
    MVBODY();                                       \
    (v) = s_;                                       \
  } while (0)

// Exact max-based rescale (epilogue only).
#define RESCALE(u, Lk) do {                         \
    float mx_ = wred_max(u);                        \
    int ke_ = (__float_as_int(mx_) >> 23) & 255;    \
    (Lk) += ke_ - 127;                              \
    (u) *= __int_as_float((254 - ke_) << 23);       \
  } while (0)

__global__ __launch_bounds__(128)
void crf_fwd(const float* __restrict__ em, const int* __restrict__ tags,
             const int* __restrict__ lengths, const float* __restrict__ trans,
             const float* __restrict__ head, const float* __restrict__ tail,
             float* __restrict__ out) {
  __shared__ float trans_lds[Nn * LDP];               // 16.6 KB
  __shared__ __align__(16) float ring[2][4 * 4 * Nn]; // per-wave 4-group em ring
  __shared__ __align__(16) float ebuf[2][Nn];         // per-wave broadcast buffer
  __shared__ float blds[Nn];
  __shared__ float scw[2];
  __shared__ float sc_ht;
  __shared__ float lbshift;

  const int bid = blockIdx.x;                         // 512 = B*C chains
  const int b = bid >> 3, c = bid & 7;
  const int tid = threadIdx.x;
  const int w = __builtin_amdgcn_readfirstlane(tid >> 6);  // 0 = fwd, 1 = bwd
  const int lane = tid & 63;
  const int bc = b * Cn + c;
  const int len = lengths[b];                         // [512, 1024]
  const int m = len >> 1;
  const int hb8 = (lane >> 5) * 8;                    // quad base for my half
  const int hb = lane & 32;                           // source base for my half
  const int px = lane ^ 32;                           // partner output index

  // ---- stage transitions[c] into LDS, stride 65 ----
  const float* tc = trans + c * Nn * Nn;
  for (int k = tid; k < Nn * Nn; k += 128) trans_lds[(k >> 6) * LDP + (k & 63)] = tc[k];
  __syncthreads();

  // ---- log_scores phase ----
  float sc = 0.f;
#pragma unroll
  for (int it = 0; it < 8; ++it) {
    int t = it * 128 + tid;
    if (t < len) {
      int tagc = tags[t * TBC + bc];
      sc += em[(size_t)t * ES + (size_t)bc * Nn + tagc];
      if (t >= 1) {
        int tagp = tags[(t - 1) * TBC + bc];
        sc += trans_lds[tagp * LDP + tagc];
      }
    }
  }
  sc = wred_sum(sc);
  if (lane == 0) scw[w] = sc;
  if (tid == 0) {
    int tag0 = tags[bc];
    int tagl = tags[(len - 1) * TBC + bc];
    sc_ht = head[c * Nn + tag0] + tail[c * Nn + tagl];
  }

  // ---- per-wave P2 fragment: 32 f32x2, sources = my half, outputs (lane, lane^32) ----
  // fwd: P2[si] = (e^{T[s][lane]}, e^{T[s][lane^32]}),  s = hb+si
  // bwd: P2[si] = (e^{T[lane][s]}, e^{T[lane^32][s]})
  f32x2 P2[32];
  if (w == 0) {
#pragma unroll
    for (int si = 0; si < 32; ++si) {
      f32x2 p;
      p.x = __expf(trans_lds[(hb + si) * LDP + lane]);
      p.y = __expf(trans_lds[(hb + si) * LDP + px]);
      P2[si] = p;
    }
  } else {
#pragma unroll
    for (int si = 0; si < 32; ++si) {
      f32x2 p;
      p.x = __expf(trans_lds[lane * LDP + hb + si]);
      p.y = __expf(trans_lds[px * LDP + hb + si]);
      P2[si] = p;
    }
  }

  float* myring = ring[w];
  float* ew = ebuf[w];
  float state = 0.f;
  float shift0 = 0.f;
  int   Lk = 0;
  float sc_st = 1.0f;   // stale rescale factor (measured one group earlier)
  int   k_st = 0;

  if (w == 0) {
    // ======== forward: steps i=0..m-1 consume em slice t=1+i ========
    float al0 = head[c * Nn + lane] + em[(size_t)bc * Nn + lane];
    shift0 = lane0(al0);
    float u = __expf(al0 - shift0);
    const float* g4 = em + (size_t)(1 + (lane >> 4)) * ES + (size_t)bc * Nn + ((lane & 15) << 2);
    const int ns = m, G = ns >> 2, r = ns & 3;

    float4 v0 = *(const float4*)(g4);
    float4 v1 = *(const float4*)(g4 + GS);
    float4 Ast = *(const float4*)(g4 + 2 * GS);
    *(float4*)&myring[0 * 256 + lane * 4] = v0;
    *(float4*)&myring[1 * 256 + lane * 4] = v1;
    float c0 = __expf(myring[0 * 256 +   0 + lane]), c1 = __expf(myring[0 * 256 +  64 + lane]),
          c2 = __expf(myring[0 * 256 + 128 + lane]), c3 = __expf(myring[0 * 256 + 192 + lane]);

    for (int g = 0; g < G; ++g) {
      u *= sc_st; Lk += k_st;                         // apply stale scale (exact 2^-k)
      int eu_ = (__builtin_amdgcn_readlane(__float_as_int(u), 0) >> 23) & 255;  // measure; applied next group
      *(float4*)&myring[((g + 2) & 3) * 256 + lane * 4] = Ast;   // commit group g+2
      Ast = *(const float4*)(g4 + (size_t)(g + 3) * GS);         // fetch group g+3 (slice <= m+12 < 1024)
      const int s1 = ((g + 1) & 3) * 256;
      float n0 = myring[s1 + lane],       n1 = myring[s1 + 64 + lane],
            n2 = myring[s1 + 128 + lane], n3 = myring[s1 + 192 + lane];
      FSTEP_LIN(u, c0); FSTEP_LIN(u, c1); FSTEP_LIN(u, c2); FSTEP_LIN(u, c3);
      k_st = eu_ - 127; sc_st = __int_as_float((254 - eu_) << 23);
      c0 = __expf(n0); c1 = __expf(n1); c2 = __expf(n2); c3 = __expf(n3);
    }
    if (r > 0) { FSTEP_LIN(u, c0); }
    if (r > 1) { FSTEP_LIN(u, c1); }
    if (r > 2) { FSTEP_LIN(u, c2); }
    RESCALE(u, Lk);                                   // exact normalize at meet point
    state = u;                                        // u_m = e^{alpha_m - A0 - Lk*ln2}
  } else {
    // ======== backward: steps k=0..nb-1 consume em slice len-1-k ========
    float tl = tail[c * Nn + lane];
    shift0 = lane0(tl);
    float v = __expf(tl - shift0);
    const int ns = len - 1 - m, G = ns >> 2, r = ns & 3;
    const float* g4 = em + (size_t)(len - 1 - (lane >> 4)) * ES + (size_t)bc * Nn + ((lane & 15) << 2);

    float4 v0 = *(const float4*)(g4);
    float4 v1 = *(const float4*)(g4 - GS);
    float4 Ast = *(const float4*)(g4 - 2 * GS);
    *(float4*)&myring[0 * 256 + lane * 4] = v0;
    *(float4*)&myring[1 * 256 + lane * 4] = v1;
    float c0 = __expf(myring[0 * 256 +   0 + lane]), c1 = __expf(myring[0 * 256 +  64 + lane]),
          c2 = __expf(myring[0 * 256 + 128 + lane]), c3 = __expf(myring[0 * 256 + 192 + lane]);

    for (int g = 0; g < G; ++g) {
      v *= sc_st; Lk += k_st;
      int eu_ = (__builtin_amdgcn_readlane(__float_as_int(v), 0) >> 23) & 255;
      *(float4*)&myring[((g + 2) & 3) * 256 + lane * 4] = Ast;
      Ast = *(const float4*)(g4 - (size_t)(g + 3) * GS);         // slice >= m-11 >= 0
      const int s1 = ((g + 1) & 3) * 256;
      float n0 = myring[s1 + lane],       n1 = myring[s1 + 64 + lane],
            n2 = myring[s1 + 128 + lane], n3 = myring[s1 + 192 + lane];
      BSTEP_LIN(v, c0); BSTEP_LIN(v, c1); BSTEP_LIN(v, c2); BSTEP_LIN(v, c3);
      k_st = eu_ - 127; sc_st = __int_as_float((254 - eu_) << 23);
      c0 = __expf(n0); c1 = __expf(n1); c2 = __expf(n2); c3 = __expf(n3);
    }
    if (r > 0) { BSTEP_LIN(v, c0); }
    if (r > 1) { BSTEP_LIN(v, c1); }
    if (r > 2) { BSTEP_LIN(v, c2); }
    RESCALE(v, Lk);                                   // exact normalize at meet point
    blds[lane] = v;                                   // v_m = e^{beta_m - B0 - Lk*ln2}
    if (lane == 0) lbshift = shift0 + (float)Lk * LN2F;
  }

  __syncthreads();                                    // both waves hit exactly once

  if (w == 0) {
    float p = state * blds[lane];                     // max ~4, positive terms
    float ssum = wred_sum(p);
    if (lane == 0) {
      float logZ = __logf(ssum) + shift0 + (float)Lk * LN2F + lbshift;
      out[bc] = scw[0] + scw[1] + sc_ht - logZ;
    }
  }
}

extern "C" void kernel_launch(void* const* d_in, const int* in_sizes, int n_in,
                              void* d_out, int out_size, void* d_ws, size_t ws_size,
                              hipStream_t stream) {
  const float* em      = (const float*)d_in[0];
  const int*   tags    = (const int*)d_in[1];
  const int*   lengths = (const int*)d_in[2];
  const float* trans   = (const float*)d_in[3];
  const float* head    = (const float*)d_in[4];
  const float* tail    = (const float*)d_in[5];
  float* out = (float*)d_out;
  crf_fwd<<<dim3(Bn * Cn), dim3(128), 0, stream>>>(em, tags, lengths, trans, head, tail, out);
}